// Round 4
// baseline (131.454 us; speedup 1.0000x reference)
//
#include <hip/hip_runtime.h>

#define NB 8
#define SD 512
#define HW 128
#define EPS 1e-5f

__device__ __forceinline__ int refl(int r) { return r < 0 ? 1 : (r > 127 ? 126 : r); }

// ============ prep: [0,2048) inorm stats | [2048,2064) style mean | [2064,4112) gen_dw
__global__ __launch_bounds__(256) void prep_k(const float* __restrict__ pred,
                                              const float* __restrict__ style,
                                              const float* __restrict__ dww,
                                              const float* __restrict__ dwb,
                                              float* __restrict__ s_ws,
                                              float* __restrict__ dw_ws,
                                              float* __restrict__ mean_ws,
                                              float* __restrict__ inv_ws) {
    __shared__ float ws4[4], wss4[4];
    int b = blockIdx.x, t = threadIdx.x;
    if (b < 2048) {
        // ---- instance-norm stats: block per (n,c) ----
        const float4* p = (const float4*)(pred + (size_t)b * HW * HW);
        float s = 0.f, ss = 0.f;
#pragma unroll
        for (int k = 0; k < 16; ++k) {
            float4 v = p[k * 256 + t];
            s  += v.x + v.y + v.z + v.w;
            ss += v.x * v.x + v.y * v.y + v.z * v.z + v.w * v.w;
        }
#pragma unroll
        for (int off = 32; off; off >>= 1) {
            s  += __shfl_down(s, off);
            ss += __shfl_down(ss, off);
        }
        if ((t & 63) == 0) { ws4[t >> 6] = s; wss4[t >> 6] = ss; }
        __syncthreads();
        if (t == 0) {
            float S  = ws4[0] + ws4[1] + ws4[2] + ws4[3];
            float SS = wss4[0] + wss4[1] + wss4[2] + wss4[3];
            float m = S * (1.f / (HW * HW));
            float var = SS * (1.f / (HW * HW)) - m * m;
            mean_ws[b] = m;
            inv_ws[b] = rsqrtf(var + EPS);
        }
    } else if (b < 2064) {
        // ---- style spatial mean ----
        int u = (b - 2048) * 256 + t;
        const float* p = style + (size_t)u * 16;
        float a = 0.f;
#pragma unroll
        for (int k = 0; k < 16; ++k) a += p[k];
        s_ws[u] = a * (1.f / 16.f);
    } else {
        // ---- dw kernel generation: wave per f, 4 f per block sharing style ----
        int bb = b - 2064;               // n fastest -> dww L2 reuse
        int n = bb & 7;
        int f = ((bb >> 3) << 2) + (t >> 6);
        int lane = t & 63;
        float acc[9];
#pragma unroll
        for (int k = 0; k < 9; ++k) acc[k] = 0.f;
#pragma unroll 2
        for (int it = 0; it < 8; ++it) {
            int c = lane + (it << 6);
            const float4* sp = (const float4*)(style + ((size_t)n * SD + c) * 16);
            float st[16];
#pragma unroll
            for (int k = 0; k < 4; ++k) {
                float4 v = sp[k];
                st[k * 4 + 0] = v.x; st[k * 4 + 1] = v.y;
                st[k * 4 + 2] = v.z; st[k * 4 + 3] = v.w;
            }
            float4 w = *(const float4*)(dww + ((size_t)f * SD + c) * 4);
#pragma unroll
            for (int p = 0; p < 3; ++p)
#pragma unroll
                for (int q = 0; q < 3; ++q)
                    acc[p * 3 + q] += st[p * 4 + q] * w.x + st[p * 4 + q + 1] * w.y
                                    + st[(p + 1) * 4 + q] * w.z + st[(p + 1) * 4 + q + 1] * w.w;
        }
#pragma unroll
        for (int k = 0; k < 9; ++k)
#pragma unroll
            for (int off = 32; off; off >>= 1) acc[k] += __shfl_down(acc[k], off);
        if (lane == 0) {
            float bias = dwb[f];
#pragma unroll
            for (int k = 0; k < 9; ++k)
                dw_ws[((size_t)n * 1024 + f) * 9 + k] = acc[k] + bias;
        }
    }
}

// ============ pointwise kernels + bias: one wave per output, coalesced ================
__global__ __launch_bounds__(256) void gen_pw_k(const float* __restrict__ s_ws,
                                                const float* __restrict__ pkw,
                                                const float* __restrict__ pkb,
                                                const float* __restrict__ pbw,
                                                const float* __restrict__ pbb,
                                                float* __restrict__ pwk,
                                                float* __restrict__ pwbias) {
    int w = blockIdx.x * 4 + (threadIdx.x >> 6);   // 0..10239
    int lane = threadIdx.x & 63;
    int n = w / 1280;
    int j = w - n * 1280;
    bool isk = j < 1024;
    const float2* wrow = (const float2*)(isk ? (pkw + (size_t)j * SD)
                                             : (pbw + (size_t)(j - 1024) * SD));
    const float2* s2 = (const float2*)(s_ws + (size_t)n * SD);
    float a = 0.f;
#pragma unroll
    for (int it = 0; it < 4; ++it) {
        int c2 = lane + (it << 6);
        float2 x = s2[c2];
        float2 v = wrow[c2];
        a += x.x * v.x + x.y * v.y;
    }
#pragma unroll
    for (int off = 32; off; off >>= 1) a += __shfl_down(a, off);
    if (lane == 0) {
        if (isk) pwk[(size_t)n * 1024 + j] = a + pkb[j];
        else     pwbias[(size_t)n * 256 + (j - 1024)] = a + pbb[j - 1024];
    }
}

// ============ fused main: inline fold + reflect-pad + grouped 3x3 ====================
// block = one 32x32 tile of one (n,g); channels staged serially, double-buffered LDS
// (~10 KB). pref(ic+1) issued BEFORE compute(ic): load latency hides under FMAs;
// lwrite lands after compute (T14 split). Low VGPR, high occupancy.
__global__ __launch_bounds__(256) void adaconv_main_k(const float* __restrict__ pred,
                                                      const float* __restrict__ dwr,
                                                      const float* __restrict__ pwk,
                                                      const float* __restrict__ pwb,
                                                      const float* __restrict__ meanv,
                                                      const float* __restrict__ invv,
                                                      float* __restrict__ out) {
    __shared__ float buf[2][34][35];
    __shared__ float wf[4][4][9];
    __shared__ float bf[4];
    int b = blockIdx.x;              // 8192 = 4tx * 4ty * 64g * 8n (tx fastest)
    int tx0 = (b & 3) << 5;
    int ty0 = ((b >> 2) & 3) << 5;
    int g = (b >> 4) & 63;
    int n = b >> 10;
    int t = threadIdx.x;
    const size_t cbase = (size_t)(n * 256 + g * 4);

    float4 pfa, pfb;
    float ph = 0.f;

    auto pref = [&](int ic) {
        const float* pc = pred + (cbase + ic) * (HW * HW);
        {
            int iy = t >> 3, cq = t & 7;
            int r = refl(ty0 + iy - 1);
            pfa = *(const float4*)(pc + r * HW + tx0 + (cq << 2));
        }
        if (t < 16) {
            int iy = 32 + (t >> 3), cq = t & 7;
            int r = refl(ty0 + iy - 1);
            pfb = *(const float4*)(pc + r * HW + tx0 + (cq << 2));
        }
        if (t < 68) {
            int iy = t >> 1, side = t & 1;
            int r = refl(ty0 + iy - 1);
            int gc = refl(side ? tx0 + 32 : tx0 - 1);
            ph = pc[r * HW + gc];
        }
    };

    auto lwrite = [&](float (*dst)[35]) {
        {
            int iy = t >> 3, cq = t & 7;
            float* d = &dst[iy][1 + (cq << 2)];
            d[0] = pfa.x; d[1] = pfa.y; d[2] = pfa.z; d[3] = pfa.w;
        }
        if (t < 16) {
            int iy = 32 + (t >> 3), cq = t & 7;
            float* d = &dst[iy][1 + (cq << 2)];
            d[0] = pfb.x; d[1] = pfb.y; d[2] = pfb.z; d[3] = pfb.w;
        }
        if (t < 68) {
            int iy = t >> 1, side = t & 1;
            dst[iy][side ? 33 : 0] = ph;
        }
    };

    pref(0);

    // inline fold: W[o,ic,k] = inv[ic] * sum_i pwk[o,i]*dwr[i,ic,k]
    //              B[o] = pwb[o] - sum_i pwk[o,i] * sum_ic mean*inv * sum_k dwr[i,ic,k]
    if (t < 144) {
        int o = t / 36, rm = t % 36, ic = rm / 9, k = rm % 9;
        float a = 0.f;
#pragma unroll
        for (int i = 0; i < 4; ++i)
            a += pwk[n * 1024 + g * 16 + o * 4 + i]
               * dwr[(size_t)(n * 1024 + g * 16 + i * 4 + ic) * 9 + k];
        wf[o][ic][k] = a * invv[cbase + ic];
    } else if (t < 148) {
        int o = t - 144;
        float cb = 0.f;
#pragma unroll
        for (int i = 0; i < 4; ++i) {
            float s2 = 0.f;
#pragma unroll
            for (int ic = 0; ic < 4; ++ic) {
                float sk = 0.f;
#pragma unroll
                for (int k = 0; k < 9; ++k)
                    sk += dwr[(size_t)(n * 1024 + g * 16 + i * 4 + ic) * 9 + k];
                s2 += meanv[cbase + ic] * invv[cbase + ic] * sk;
            }
            cb += pwk[n * 1024 + g * 16 + o * 4 + i] * s2;
        }
        bf[o] = pwb[cbase + o] - cb;
    }

    lwrite(buf[0]);
    __syncthreads();

    int cq = t & 7, row = t >> 3;     // out row ty0+row, cols tx0+4cq..+3
    float acc[4][4];
#pragma unroll
    for (int o = 0; o < 4; ++o) {
        float bb = bf[o];
#pragma unroll
        for (int p = 0; p < 4; ++p) acc[o][p] = bb;
    }

#pragma unroll
    for (int ic = 0; ic < 4; ++ic) {
        if (ic < 3) pref(ic + 1);            // issue next-channel loads (in flight)
        const float (*bb)[35] = buf[ic & 1];
#pragma unroll
        for (int kh = 0; kh < 3; ++kh) {
            float v[6];
            const float* rp = &bb[row + kh][cq << 2];
#pragma unroll
            for (int c = 0; c < 6; ++c) v[c] = rp[c];
#pragma unroll
            for (int o = 0; o < 4; ++o) {
                float w0 = wf[o][ic][kh * 3 + 0];
                float w1 = wf[o][ic][kh * 3 + 1];
                float w2 = wf[o][ic][kh * 3 + 2];
#pragma unroll
                for (int p = 0; p < 4; ++p)
                    acc[o][p] = fmaf(w0, v[p], fmaf(w1, v[p + 1], fmaf(w2, v[p + 2], acc[o][p])));
            }
        }
        if (ic < 3) {
            lwrite(buf[(ic + 1) & 1]);       // waits vmcnt (likely drained), LDS write
            __syncthreads();                 // next buffer ready / old buffer free
        }
    }

#pragma unroll
    for (int o = 0; o < 4; ++o) {
        *(float4*)(out + (cbase + o) * (HW * HW) + (ty0 + row) * HW + tx0 + (cq << 2)) =
            make_float4(acc[o][0], acc[o][1], acc[o][2], acc[o][3]);
    }
}

extern "C" void kernel_launch(void* const* d_in, const int* in_sizes, int n_in,
                              void* d_out, int out_size, void* d_ws, size_t ws_size,
                              hipStream_t stream) {
    const float* style = (const float*)d_in[0];   // [8,512,4,4]
    const float* pred  = (const float*)d_in[1];   // [8,256,128,128]
    const float* dww   = (const float*)d_in[2];   // [1024,512,2,2]
    const float* dwb   = (const float*)d_in[3];   // [1024]
    const float* pkw   = (const float*)d_in[4];   // [1024,512]
    const float* pkb   = (const float*)d_in[5];   // [1024]
    const float* pbw   = (const float*)d_in[6];   // [256,512]
    const float* pbb   = (const float*)d_in[7];   // [256]
    float* out = (float*)d_out;

    float* ws      = (float*)d_ws;
    float* s_ws    = ws;            // 4096
    float* dw_ws   = ws + 4096;     // 73728 (raw generated dw kernels)
    float* pwk_ws  = ws + 77824;    // 8192
    float* pwb_ws  = ws + 86016;    // 2048
    float* mean_ws = ws + 88064;    // 2048
    float* inv_ws  = ws + 90112;    // 2048  (end: 92160 floats)

    prep_k<<<4112, 256, 0, stream>>>(pred, style, dww, dwb, s_ws, dw_ws, mean_ws, inv_ws);
    gen_pw_k<<<2560, 256, 0, stream>>>(s_ws, pkw, pkb, pbw, pbb, pwk_ws, pwb_ws);
    adaconv_main_k<<<8192, 256, 0, stream>>>(pred, dw_ws, pwk_ws, pwb_ws, mean_ws, inv_ws, out);
}

// Round 5
// 122.595 us; speedup vs baseline: 1.0723x; 1.0723x over previous
//
#include <hip/hip_runtime.h>

#define NB 8
#define SD 512
#define HW 128
#define EPS 1e-5f

__device__ __forceinline__ int refl(int r) { return r < 0 ? 1 : (r > 127 ? 126 : r); }

// ============ prep: [0,2048) inorm stats | [2048,2064) style mean | [2064,4112) gen_dw
__global__ __launch_bounds__(256) void prep_k(const float* __restrict__ pred,
                                              const float* __restrict__ style,
                                              const float* __restrict__ dww,
                                              const float* __restrict__ dwb,
                                              float* __restrict__ s_ws,
                                              float* __restrict__ dw_ws,
                                              float* __restrict__ mean_ws,
                                              float* __restrict__ inv_ws) {
    __shared__ float ws4[4], wss4[4];
    int b = blockIdx.x, t = threadIdx.x;
    if (b < 2048) {
        // ---- instance-norm stats: block per (n,c) ----
        const float4* p = (const float4*)(pred + (size_t)b * HW * HW);
        float s = 0.f, ss = 0.f;
#pragma unroll
        for (int k = 0; k < 16; ++k) {
            float4 v = p[k * 256 + t];
            s  += v.x + v.y + v.z + v.w;
            ss += v.x * v.x + v.y * v.y + v.z * v.z + v.w * v.w;
        }
#pragma unroll
        for (int off = 32; off; off >>= 1) {
            s  += __shfl_down(s, off);
            ss += __shfl_down(ss, off);
        }
        if ((t & 63) == 0) { ws4[t >> 6] = s; wss4[t >> 6] = ss; }
        __syncthreads();
        if (t == 0) {
            float S  = ws4[0] + ws4[1] + ws4[2] + ws4[3];
            float SS = wss4[0] + wss4[1] + wss4[2] + wss4[3];
            float m = S * (1.f / (HW * HW));
            float var = SS * (1.f / (HW * HW)) - m * m;
            mean_ws[b] = m;
            inv_ws[b] = rsqrtf(var + EPS);
        }
    } else if (b < 2064) {
        // ---- style spatial mean ----
        int u = (b - 2048) * 256 + t;
        const float* p = style + (size_t)u * 16;
        float a = 0.f;
#pragma unroll
        for (int k = 0; k < 16; ++k) a += p[k];
        s_ws[u] = a * (1.f / 16.f);
    } else {
        // ---- dw kernel generation: wave per f, 4 f per block sharing style ----
        int bb = b - 2064;               // n fastest -> dww L2 reuse
        int n = bb & 7;
        int f = ((bb >> 3) << 2) + (t >> 6);
        int lane = t & 63;
        float acc[9];
#pragma unroll
        for (int k = 0; k < 9; ++k) acc[k] = 0.f;
#pragma unroll 2
        for (int it = 0; it < 8; ++it) {
            int c = lane + (it << 6);
            const float4* sp = (const float4*)(style + ((size_t)n * SD + c) * 16);
            float st[16];
#pragma unroll
            for (int k = 0; k < 4; ++k) {
                float4 v = sp[k];
                st[k * 4 + 0] = v.x; st[k * 4 + 1] = v.y;
                st[k * 4 + 2] = v.z; st[k * 4 + 3] = v.w;
            }
            float4 w = *(const float4*)(dww + ((size_t)f * SD + c) * 4);
#pragma unroll
            for (int p = 0; p < 3; ++p)
#pragma unroll
                for (int q = 0; q < 3; ++q)
                    acc[p * 3 + q] += st[p * 4 + q] * w.x + st[p * 4 + q + 1] * w.y
                                    + st[(p + 1) * 4 + q] * w.z + st[(p + 1) * 4 + q + 1] * w.w;
        }
#pragma unroll
        for (int k = 0; k < 9; ++k)
#pragma unroll
            for (int off = 32; off; off >>= 1) acc[k] += __shfl_down(acc[k], off);
        if (lane == 0) {
            float bias = dwb[f];
#pragma unroll
            for (int k = 0; k < 9; ++k)
                dw_ws[((size_t)n * 1024 + f) * 9 + k] = acc[k] + bias;
        }
    }
}

// ============ pointwise kernels + bias: one wave per output, coalesced ================
__global__ __launch_bounds__(256) void gen_pw_k(const float* __restrict__ s_ws,
                                                const float* __restrict__ pkw,
                                                const float* __restrict__ pkb,
                                                const float* __restrict__ pbw,
                                                const float* __restrict__ pbb,
                                                float* __restrict__ pwk,
                                                float* __restrict__ pwbias) {
    int w = blockIdx.x * 4 + (threadIdx.x >> 6);   // 0..10239
    int lane = threadIdx.x & 63;
    int n = w / 1280;
    int j = w - n * 1280;
    bool isk = j < 1024;
    const float2* wrow = (const float2*)(isk ? (pkw + (size_t)j * SD)
                                             : (pbw + (size_t)(j - 1024) * SD));
    const float2* s2 = (const float2*)(s_ws + (size_t)n * SD);
    float a = 0.f;
#pragma unroll
    for (int it = 0; it < 4; ++it) {
        int c2 = lane + (it << 6);
        float2 x = s2[c2];
        float2 v = wrow[c2];
        a += x.x * v.x + x.y * v.y;
    }
#pragma unroll
    for (int off = 32; off; off >>= 1) a += __shfl_down(a, off);
    if (lane == 0) {
        if (isk) pwk[(size_t)n * 1024 + j] = a + pkb[j];
        else     pwbias[(size_t)n * 256 + (j - 1024)] = a + pbb[j - 1024];
    }
}

// ============ fold: W[o,ic,k] = sum_i pwk[o,i]*inv[ic]*dw[i,ic,k] (in-place) ==========
//              B[o] = pwbias[o] - sum_i pwk[o,i] * sum_ic m*inv * sum_k dw[i,ic,k]
__global__ __launch_bounds__(192) void fold_k(float* __restrict__ dw_ws,
                                              const float* __restrict__ pwk_ws,
                                              float* __restrict__ pwb_ws,
                                              const float* __restrict__ mean_ws,
                                              const float* __restrict__ inv_ws) {
    __shared__ float dwl[144], pwkl[16], invl[4], msc[4], pwbl[4];
    int b = blockIdx.x;              // n*64+g
    int n = b >> 6, g = b & 63;
    int t = threadIdx.x;
    size_t dbase = (size_t)(n * 1024 + g * 16) * 9;
    if (t < 144) dwl[t] = dw_ws[dbase + t];
    else if (t < 160) pwkl[t - 144] = pwk_ws[(size_t)n * 1024 + g * 16 + (t - 144)];
    else if (t < 164) {
        int ic = t - 160;
        float m = mean_ws[n * 256 + g * 4 + ic];
        float s = inv_ws[n * 256 + g * 4 + ic];
        invl[ic] = s; msc[ic] = m * s;
    } else if (t < 168) {
        pwbl[t - 164] = pwb_ws[n * 256 + g * 4 + (t - 164)];
    }
    __syncthreads();
    if (t < 144) {
        int o = t / 36, rm = t % 36, ic = rm / 9, k = rm % 9;
        float a = 0.f;
#pragma unroll
        for (int i = 0; i < 4; ++i) a += pwkl[o * 4 + i] * dwl[(i * 4 + ic) * 9 + k];
        dw_ws[dbase + (size_t)(o * 4 + ic) * 9 + k] = a * invl[ic];
    } else if (t < 148) {
        int o = t - 144;
        float cb = 0.f;
#pragma unroll
        for (int i = 0; i < 4; ++i) {
            float s2 = 0.f;
#pragma unroll
            for (int ic = 0; ic < 4; ++ic) {
                float sk = 0.f;
#pragma unroll
                for (int k = 0; k < 9; ++k) sk += dwl[(i * 4 + ic) * 9 + k];
                s2 += msc[ic] * sk;
            }
            cb += pwkl[o * 4 + i] * s2;
        }
        pwb_ws[n * 256 + g * 4 + o] = pwbl[o] - cb;
    }
}

// ============ fused main: reflect-pad + folded grouped 3x3 -> out =====================
// One 32x32 tile per 256-thr block. ALL global loads (4 channels + halos + weights)
// issued first (max MLP), then LDS writes, one barrier, compute, store. VGPR-lean.
__global__ __launch_bounds__(256) void adaconv_main_k(const float* __restrict__ pred,
                                                      const float* __restrict__ Wf,
                                                      const float* __restrict__ Bf,
                                                      float* __restrict__ out) {
    __shared__ float tile[4][34][35];
    __shared__ float wf[144];
    __shared__ float bfs[4];
    int b = blockIdx.x;              // 8192 = 4tx * 4ty * 64g * 8n (tx fastest)
    int tx0 = (b & 3) << 5;
    int ty0 = ((b >> 2) & 3) << 5;
    int g = (b >> 4) & 63;
    int n = b >> 10;
    int t = threadIdx.x;
    const size_t cbase = (size_t)(n * 256 + g * 4);

    // ---- issue ALL global loads (weights + 4-channel tile + halos) ----
    float wreg = 0.f, breg = 0.f;
    if (t < 144) wreg = Wf[(size_t)(n * 64 + g) * 144 + t];
    if (t >= 160 && t < 164) breg = Bf[(size_t)(n * 64 + g) * 4 + (t - 160)];

    float4 pf[4], pf4;
    float ph0 = 0.f, ph1 = 0.f;
#pragma unroll
    for (int k = 0; k < 4; ++k) {
        int j = t + (k << 8);
        int ic = j / 272; int rm = j - ic * 272;
        int iy = rm >> 3, cq = rm & 7;
        int r = refl(ty0 + iy - 1);
        pf[k] = *(const float4*)(pred + (cbase + ic) * (HW * HW) + r * HW + tx0 + (cq << 2));
    }
    if (t < 64) {
        int rm = t + 208;            // ic = 3, elems 208..271
        int iy = rm >> 3, cq = rm & 7;
        int r = refl(ty0 + iy - 1);
        pf4 = *(const float4*)(pred + (cbase + 3) * (HW * HW) + r * HW + tx0 + (cq << 2));
    }
    {
        int ic = t / 68; int rm = t - ic * 68;
        int iy = rm >> 1, side = rm & 1;
        int r = refl(ty0 + iy - 1);
        int gc = refl(side ? tx0 + 32 : tx0 - 1);
        ph0 = pred[(cbase + ic) * (HW * HW) + r * HW + gc];
    }
    if (t < 16) {
        int rm = t + 52;             // ic = 3, halo elems 52..67
        int iy = rm >> 1, side = rm & 1;
        int r = refl(ty0 + iy - 1);
        int gc = refl(side ? tx0 + 32 : tx0 - 1);
        ph1 = pred[(cbase + 3) * (HW * HW) + r * HW + gc];
    }

    // ---- write everything to LDS ----
    if (t < 144) wf[t] = wreg;
    if (t >= 160 && t < 164) bfs[t - 160] = breg;
#pragma unroll
    for (int k = 0; k < 4; ++k) {
        int j = t + (k << 8);
        int ic = j / 272; int rm = j - ic * 272;
        int iy = rm >> 3, cq = rm & 7;
        float* d = &tile[ic][iy][1 + (cq << 2)];
        d[0] = pf[k].x; d[1] = pf[k].y; d[2] = pf[k].z; d[3] = pf[k].w;
    }
    if (t < 64) {
        int rm = t + 208;
        int iy = rm >> 3, cq = rm & 7;
        float* d = &tile[3][iy][1 + (cq << 2)];
        d[0] = pf4.x; d[1] = pf4.y; d[2] = pf4.z; d[3] = pf4.w;
    }
    {
        int ic = t / 68; int rm = t - ic * 68;
        tile[ic][rm >> 1][(rm & 1) ? 33 : 0] = ph0;
    }
    if (t < 16) {
        int rm = t + 52;
        tile[3][rm >> 1][(rm & 1) ? 33 : 0] = ph1;
    }
    __syncthreads();

    // ---- compute ----
    int cq = t & 7, row = t >> 3;    // out row ty0+row, cols tx0+4cq..+3
    float acc[4][4];
#pragma unroll
    for (int o = 0; o < 4; ++o) {
        float bb = bfs[o];
#pragma unroll
        for (int p = 0; p < 4; ++p) acc[o][p] = bb;
    }
#pragma unroll
    for (int ic = 0; ic < 4; ++ic) {
#pragma unroll
        for (int kh = 0; kh < 3; ++kh) {
            float v[6];
            const float* rp = &tile[ic][row + kh][cq << 2];
#pragma unroll
            for (int c = 0; c < 6; ++c) v[c] = rp[c];
#pragma unroll
            for (int o = 0; o < 4; ++o) {
                float w0 = wf[(o * 4 + ic) * 9 + kh * 3 + 0];
                float w1 = wf[(o * 4 + ic) * 9 + kh * 3 + 1];
                float w2 = wf[(o * 4 + ic) * 9 + kh * 3 + 2];
#pragma unroll
                for (int p = 0; p < 4; ++p)
                    acc[o][p] = fmaf(w0, v[p], fmaf(w1, v[p + 1], fmaf(w2, v[p + 2], acc[o][p])));
            }
        }
    }

#pragma unroll
    for (int o = 0; o < 4; ++o) {
        *(float4*)(out + (cbase + o) * (HW * HW) + (ty0 + row) * HW + tx0 + (cq << 2)) =
            make_float4(acc[o][0], acc[o][1], acc[o][2], acc[o][3]);
    }
}

extern "C" void kernel_launch(void* const* d_in, const int* in_sizes, int n_in,
                              void* d_out, int out_size, void* d_ws, size_t ws_size,
                              hipStream_t stream) {
    const float* style = (const float*)d_in[0];   // [8,512,4,4]
    const float* pred  = (const float*)d_in[1];   // [8,256,128,128]
    const float* dww   = (const float*)d_in[2];   // [1024,512,2,2]
    const float* dwb   = (const float*)d_in[3];   // [1024]
    const float* pkw   = (const float*)d_in[4];   // [1024,512]
    const float* pkb   = (const float*)d_in[5];   // [1024]
    const float* pbw   = (const float*)d_in[6];   // [256,512]
    const float* pbb   = (const float*)d_in[7];   // [256]
    float* out = (float*)d_out;

    float* ws      = (float*)d_ws;
    float* s_ws    = ws;            // 4096
    float* dw_ws   = ws + 4096;     // 73728 (raw dw kernels, folded in place)
    float* pwk_ws  = ws + 77824;    // 8192
    float* pwb_ws  = ws + 86016;    // 2048 (folded bias in place)
    float* mean_ws = ws + 88064;    // 2048
    float* inv_ws  = ws + 90112;    // 2048  (end: 92160 floats)

    prep_k<<<4112, 256, 0, stream>>>(pred, style, dww, dwb, s_ws, dw_ws, mean_ws, inv_ws);
    gen_pw_k<<<2560, 256, 0, stream>>>(s_ws, pkw, pkb, pbw, pbb, pwk_ws, pwb_ws);
    fold_k<<<NB * 64, 192, 0, stream>>>(dw_ws, pwk_ws, pwb_ws, mean_ws, inv_ws);
    adaconv_main_k<<<8192, 256, 0, stream>>>(pred, dw_ws, pwb_ws, out);
}